// Round 8
// baseline (131.090 us; speedup 1.0000x reference)
//
#include <hip/hip_runtime.h>

#define B_ 8
#define N_ 4096
#define C_ 768
#define NP_ 4095
#define H_ 16
#define D_ 48
#define HID_ 3072
#define SCALE 0.14433756729740643f  // 1/sqrt(48)

typedef unsigned short u16;
typedef unsigned int u32;
typedef __attribute__((ext_vector_type(4))) float f32x4;
typedef __attribute__((ext_vector_type(8))) short short8;

__device__ __forceinline__ u32 f2bf_bits(float f){
  union { float f; u32 i; } v; v.f = f;
  return (v.i + 0x7fffu + ((v.i >> 16) & 1u)) >> 16;
}
__device__ __forceinline__ u16 f2bf(float f){ return (u16)f2bf_bits(f); }
__device__ __forceinline__ u32 pack2(float a, float b){
  return f2bf_bits(a) | (f2bf_bits(b) << 16);
}

// ---------------- k_q: qv[b,j] = LN(x[b,4095]) @ Wq[:,j] + bq[j] -------------
__global__ __launch_bounds__(256) void k_q(const float* __restrict__ x,
    const float* __restrict__ Wq, const float* __restrict__ bq,
    float* __restrict__ qv)
{
  int b = blockIdx.y, t = threadIdx.x;
  int j0 = blockIdx.x*32;
  __shared__ float xs[C_];
  __shared__ float red[32][9];
  __shared__ float redA[4], redB[4];
  const float* xr = x + ((size_t)b*N_ + NP_)*C_;
  float v0 = xr[t], v1 = xr[t+256], v2 = xr[t+512];
  float s = v0+v1+v2, q = v0*v0+v1*v1+v2*v2;
  #pragma unroll
  for (int off=32; off; off>>=1){ s += __shfl_xor(s,off); q += __shfl_xor(q,off); }
  int w = t>>6, l = t&63;
  if (l==0){ redA[w]=s; redB[w]=q; }
  __syncthreads();
  s = redA[0]+redA[1]+redA[2]+redA[3];
  q = redB[0]+redB[1]+redB[2]+redB[3];
  float mean = s*(1.f/C_), var = q*(1.f/C_) - mean*mean;
  float rstd = rsqrtf(var + 1e-6f);
  xs[t] = (v0-mean)*rstd; xs[t+256] = (v1-mean)*rstd; xs[t+512] = (v2-mean)*rstd;
  __syncthreads();
  int jl = t&31, part = t>>5;
  const float* wp = Wq + (size_t)(part*96)*C_ + j0 + jl;
  const float* xp = xs + part*96;
  float acc = 0.f;
  #pragma unroll 8
  for (int c=0;c<96;c++) acc += xp[c]*wp[(size_t)c*C_];
  red[jl][part] = acc;
  __syncthreads();
  if (part==0){
    float a = bq[j0+jl];
    #pragma unroll
    for (int p=0;p<8;p++) a += red[jl][p];
    qv[(size_t)b*C_ + j0 + jl] = a;
  }
}

// --- k_qw: qWb[b,h,c] = bf16( sum_d qv[b,h*48+d]*Wkv[c, h*48+d] ) ------------
__global__ __launch_bounds__(256) void k_qw(const float* __restrict__ qv,
    const float* __restrict__ Wkv, u16* __restrict__ qWb)
{
  int b = blockIdx.y, t = threadIdx.x;
  int c0 = blockIdx.x*16;
  __shared__ float qs[C_];
  for (int u=t; u<C_; u+=256) qs[u] = qv[(size_t)b*C_+u];
  __syncthreads();
  int h = t&15, cl = t>>4;
  int c = c0 + cl;
  const float* wp = Wkv + (size_t)c*(2*C_) + h*D_;
  const float* qh = qs + h*D_;
  float acc = 0.f;
  #pragma unroll
  for (int d=0; d<D_; d++) acc += qh[d]*wp[d];
  qWb[((size_t)b*H_ + h)*C_ + c] = f2bf(acc);
}

// ---- k_attn v3: low-LDS. P1: copy+stats (stream). P2: MFMA sim (L2 re-read).
// ----           P3: ctx from global (L2-hot) + wexp broadcast. --------------
__global__ __launch_bounds__(256) void k_attn(const float* __restrict__ x,
    const u16* __restrict__ qWb, float* __restrict__ outp,
    float* __restrict__ ctx, float* __restrict__ denom)
{
  int b = blockIdx.y;
  int tid = threadIdx.x;
  int w = tid>>6, l = tid&63;
  int kblk = blockIdx.x*64;
  __shared__ float wexp[64][20];
  __shared__ float2 stl[64];
  const size_t xb = (size_t)b*N_*C_;

  // ---- P1: copy + LN stats, wave w handles rows it*4+w ----
  #pragma unroll 4
  for (int it=0; it<16; ++it){
    int r = it*4 + w;
    int kt = kblk + r;
    const float4* rp = (const float4*)(x + xb + (size_t)kt*C_);
    float4* op = (float4*)(outp + xb + (size_t)kt*C_);
    float4 v0 = rp[l], v1 = rp[l+64], v2 = rp[l+128];
    op[l] = v0; op[l+64] = v1; op[l+128] = v2;
    float s = v0.x+v0.y+v0.z+v0.w + v1.x+v1.y+v1.z+v1.w + v2.x+v2.y+v2.z+v2.w;
    float q = v0.x*v0.x+v0.y*v0.y+v0.z*v0.z+v0.w*v0.w
            + v1.x*v1.x+v1.y*v1.y+v1.z*v1.z+v1.w*v1.w
            + v2.x*v2.x+v2.y*v2.y+v2.z*v2.z+v2.w*v2.w;
    #pragma unroll
    for (int off=32; off; off>>=1){ s += __shfl_xor(s,off); q += __shfl_xor(q,off); }
    if (l==0){
      float mean = s*(1.f/C_), var = q*(1.f/C_) - mean*mean;
      stl[r] = make_float2(mean, rsqrtf(var + 1e-6f));
    }
  }
  __syncthreads();

  // ---- P2: MFMA sim, wave w -> rows w*16..w*16+15, 16 heads, K=768 ----
  {
    int arow = w*16 + (l&15);
    float2 ms = stl[arow];
    const float* ar = x + xb + (size_t)(kblk + arow)*C_ + (l>>4)*8;
    const u16* br = qWb + ((size_t)b*H_ + (l&15))*C_ + (l>>4)*8;
    f32x4 acc = {0.f,0.f,0.f,0.f};
    #pragma unroll 6
    for (int s2=0;s2<24;s2++){
      float4 g0 = *(const float4*)(ar + s2*32);
      float4 g1 = *(const float4*)(ar + s2*32 + 4);
      uint4 nv;
      nv.x = pack2((g0.x-ms.x)*ms.y, (g0.y-ms.x)*ms.y);
      nv.y = pack2((g0.z-ms.x)*ms.y, (g0.w-ms.x)*ms.y);
      nv.z = pack2((g1.x-ms.x)*ms.y, (g1.y-ms.x)*ms.y);
      nv.w = pack2((g1.z-ms.x)*ms.y, (g1.w-ms.x)*ms.y);
      union{uint4 u; short8 v;} A, Bf;
      A.u = nv;
      Bf.u = *(const uint4*)(br + s2*32);
      acc = __builtin_amdgcn_mfma_f32_16x16x32_bf16(A.v, Bf.v, acc, 0,0,0);
    }
    // D[m][n]: head n = l&15, row m = (l>>4)*4 + r
    int hh = l&15, mb = (l>>4)*4;
    #pragma unroll
    for (int r=0;r<4;r++){
      int rr = w*16 + mb + r;
      int kt = kblk + rr;
      wexp[rr][hh] = (kt < NP_) ? __expf(acc[r]*SCALE) : 0.f;
    }
  }
  __syncthreads();

  // ---- denom ----
  if (tid < 16){
    float ds = 0.f;
    #pragma unroll 8
    for (int k=0;k<64;k++) ds += wexp[k][tid];
    atomicAdd(denom + (size_t)b*H_ + tid, ds);
  }

  // ---- P3: ctx, wave w owns cols [w*192, w*192+192) ----
  int c0 = w*192;
  float accA[H_], accB[H_], accC[H_];
  #pragma unroll
  for (int h=0;h<H_;h++){ accA[h]=0.f; accB[h]=0.f; accC[h]=0.f; }
  for (int k=0;k<64;k++){
    int kt = kblk + k;
    const float* xr = x + xb + (size_t)kt*C_ + c0;
    float2 ms = stl[k];
    float xA = (xr[l]     - ms.x)*ms.y;
    float xB = (xr[l+64]  - ms.x)*ms.y;
    float xC = (xr[l+128] - ms.x)*ms.y;
    const float4* wp4 = (const float4*)&wexp[k][0];
    float4 w0 = wp4[0], w1 = wp4[1], w2 = wp4[2], w3 = wp4[3];
    accA[0]+=w0.x*xA; accA[1]+=w0.y*xA; accA[2]+=w0.z*xA; accA[3]+=w0.w*xA;
    accA[4]+=w1.x*xA; accA[5]+=w1.y*xA; accA[6]+=w1.z*xA; accA[7]+=w1.w*xA;
    accA[8]+=w2.x*xA; accA[9]+=w2.y*xA; accA[10]+=w2.z*xA; accA[11]+=w2.w*xA;
    accA[12]+=w3.x*xA; accA[13]+=w3.y*xA; accA[14]+=w3.z*xA; accA[15]+=w3.w*xA;
    accB[0]+=w0.x*xB; accB[1]+=w0.y*xB; accB[2]+=w0.z*xB; accB[3]+=w0.w*xB;
    accB[4]+=w1.x*xB; accB[5]+=w1.y*xB; accB[6]+=w1.z*xB; accB[7]+=w1.w*xB;
    accB[8]+=w2.x*xB; accB[9]+=w2.y*xB; accB[10]+=w2.z*xB; accB[11]+=w2.w*xB;
    accB[12]+=w3.x*xB; accB[13]+=w3.y*xB; accB[14]+=w3.z*xB; accB[15]+=w3.w*xB;
    accC[0]+=w0.x*xC; accC[1]+=w0.y*xC; accC[2]+=w0.z*xC; accC[3]+=w0.w*xC;
    accC[4]+=w1.x*xC; accC[5]+=w1.y*xC; accC[6]+=w1.z*xC; accC[7]+=w1.w*xC;
    accC[8]+=w2.x*xC; accC[9]+=w2.y*xC; accC[10]+=w2.z*xC; accC[11]+=w2.w*xC;
    accC[12]+=w3.x*xC; accC[13]+=w3.y*xC; accC[14]+=w3.z*xC; accC[15]+=w3.w*xC;
  }
  float* cb = ctx + (size_t)b*H_*C_;
  #pragma unroll
  for (int h=0;h<H_;h++){
    atomicAdd(cb + h*C_ + c0 + l,       accA[h]);
    atomicAdd(cb + h*C_ + c0 + 64 + l,  accB[h]);
    atomicAdd(cb + h*C_ + c0 + 128 + l, accC[h]);
  }
}

// ------ k_v: oat[b,t] = (ctx[b,h(t),:]/denom[b,h(t)]) @ Wv[:,t] + bv[t] ------
__global__ __launch_bounds__(256) void k_v(const float* __restrict__ ctx,
    const float* __restrict__ denom, const float* __restrict__ Wkv,
    const float* __restrict__ bkv, float* __restrict__ oat)
{
  int b = blockIdx.y, t = threadIdx.x;
  int t0 = blockIdx.x*32;
  int h0 = t0/D_;
  int h1 = (t0+31)/D_; if (h1 > H_-1) h1 = H_-1;
  __shared__ float cn[2][C_];
  __shared__ float red[32][9];
  float inv0 = 1.f/denom[(size_t)b*H_+h0];
  float inv1 = 1.f/denom[(size_t)b*H_+h1];
  for (int u=t; u<C_; u+=256){
    cn[0][u] = ctx[((size_t)b*H_+h0)*C_+u]*inv0;
    cn[1][u] = ctx[((size_t)b*H_+h1)*C_+u]*inv1;
  }
  __syncthreads();
  int jl = t&31, part = t>>5;
  int tt = t0 + jl;
  int hi = (tt/D_) - h0;   // 0 or 1
  const float* wp = Wkv + (size_t)(part*96)*(2*C_) + C_ + tt;
  const float* cp = cn[hi] + part*96;
  float acc = 0.f;
  #pragma unroll 8
  for (int c=0;c<96;c++) acc += cp[c]*wp[(size_t)c*(2*C_)];
  red[jl][part] = acc;
  __syncthreads();
  if (part==0){
    float a = bkv[C_ + tt];
    #pragma unroll
    for (int p=0;p<8;p++) a += red[jl][p];
    oat[(size_t)b*C_ + tt] = a;
  }
}

// ------- k_o: lastb[b,t] = x[b,4095,t] + oat[b] @ Wo[:,t] + bo[t] ------------
__global__ __launch_bounds__(256) void k_o(const float* __restrict__ x,
    const float* __restrict__ oat, const float* __restrict__ Wo,
    const float* __restrict__ bo, float* __restrict__ lastb)
{
  int b = blockIdx.y, t = threadIdx.x;
  int t0 = blockIdx.x*32;
  __shared__ float xs[C_];
  __shared__ float red[32][9];
  for (int u=t; u<C_; u+=256) xs[u] = oat[(size_t)b*C_+u];
  __syncthreads();
  int jl = t&31, part = t>>5;
  int tt = t0 + jl;
  const float* wp = Wo + (size_t)(part*96)*C_ + tt;
  const float* xp = xs + part*96;
  float acc = 0.f;
  #pragma unroll 8
  for (int c=0;c<96;c++) acc += xp[c]*wp[(size_t)c*C_];
  red[jl][part] = acc;
  __syncthreads();
  if (part==0){
    float a = bo[tt];
    #pragma unroll
    for (int p=0;p<8;p++) a += red[jl][p];
    lastb[(size_t)b*C_ + tt] = x[((size_t)b*N_ + NP_)*C_ + tt] + a;
  }
}

// --- k_mlp1 (batched): hid[b] = gelu(LN(lastb[b]) @ W1 + b1), W1 read once ---
__global__ __launch_bounds__(256) void k_mlp1(const float* __restrict__ lastb,
    const float* __restrict__ W1, const float* __restrict__ b1,
    float* __restrict__ hid)
{
  int t = threadIdx.x;
  int j0 = blockIdx.x*16;
  __shared__ float xs[B_][C_];
  __shared__ float red[16][16][8];
  {
    int bb = t>>5, sub = t&31;
    const float* xr = lastb + (size_t)bb*C_;
    float s=0.f, q=0.f;
    #pragma unroll
    for (int j=0;j<24;j++){ float v = xr[sub+32*j]; s += v; q += v*v; }
    #pragma unroll
    for (int off=1; off<32; off<<=1){ s += __shfl_xor(s,off); q += __shfl_xor(q,off); }
    float mean = s*(1.f/C_), var = q*(1.f/C_) - mean*mean;
    float rstd = rsqrtf(var + 1e-6f);
    #pragma unroll
    for (int j=0;j<24;j++){ xs[bb][sub+32*j] = (xr[sub+32*j]-mean)*rstd; }
  }
  __syncthreads();
  int jl = t&15, part = t>>4;
  const float* wp = W1 + (size_t)(part*48)*HID_ + j0 + jl;
  float acc[B_];
  #pragma unroll
  for (int bb=0;bb<B_;bb++) acc[bb]=0.f;
  for (int c=0;c<48;c++){
    float wv = wp[(size_t)c*HID_];
    int cc = part*48 + c;
    #pragma unroll
    for (int bb=0;bb<B_;bb++) acc[bb] += xs[bb][cc]*wv;
  }
  #pragma unroll
  for (int bb=0;bb<B_;bb++) red[jl][part][bb] = acc[bb];
  __syncthreads();
  if (t < 128){
    int jl2 = t&15, bb = t>>4;
    float a = b1[j0+jl2];
    #pragma unroll
    for (int p=0;p<16;p++) a += red[jl2][p][bb];
    float t3 = a + 0.044715f*a*a*a;
    float g = 0.5f*a*(1.f + tanhf(0.7978845608f*t3));
    hid[(size_t)bb*HID_ + j0 + jl2] = g;
  }
}

// --- k_mlp2 (batched): out[b,4095,:] = lastb[b] + hid[b] @ W2 + b2 -----------
__global__ __launch_bounds__(256) void k_mlp2(const float* __restrict__ hid,
    const float* __restrict__ W2, const float* __restrict__ b2,
    const float* __restrict__ lastb, float* __restrict__ outp)
{
  int t = threadIdx.x;
  int c0 = blockIdx.x*8;
  __shared__ float red[8][32][8];
  int ccl = t&7, part = t>>3;
  const float* wp = W2 + (size_t)(part*96)*C_ + c0 + ccl;
  float acc[B_];
  #pragma unroll
  for (int bb=0;bb<B_;bb++) acc[bb]=0.f;
  for (int j=0;j<96;j++){
    float wv = wp[(size_t)j*C_];
    int jj = part*96 + j;
    #pragma unroll
    for (int bb=0;bb<B_;bb++) acc[bb] += hid[(size_t)bb*HID_ + jj]*wv;
  }
  #pragma unroll
  for (int bb=0;bb<B_;bb++) red[ccl][part][bb] = acc[bb];
  __syncthreads();
  if (t < 64){
    int cc2 = t&7, bb = t>>3;
    float a = 0.f;
    #pragma unroll
    for (int p=0;p<32;p++) a += red[cc2][p][bb];
    int cc = c0 + cc2;
    a += b2[cc] + lastb[(size_t)bb*C_ + cc];
    outp[((size_t)bb*N_ + NP_)*C_ + cc] = a;
  }
}

extern "C" void kernel_launch(void* const* d_in, const int* in_sizes, int n_in,
                              void* d_out, int out_size, void* d_ws, size_t ws_size,
                              hipStream_t stream)
{
  (void)in_sizes; (void)n_in; (void)out_size; (void)ws_size;
  const float* x   = (const float*)d_in[0];
  const float* Wq  = (const float*)d_in[1];
  const float* bq  = (const float*)d_in[2];
  const float* Wkv = (const float*)d_in[3];
  const float* bkv = (const float*)d_in[4];
  const float* Wo  = (const float*)d_in[5];
  const float* bo  = (const float*)d_in[6];
  const float* W1  = (const float*)d_in[7];
  const float* b1  = (const float*)d_in[8];
  const float* W2  = (const float*)d_in[9];
  const float* b2  = (const float*)d_in[10];
  float* outp = (float*)d_out;
  float* ws = (float*)d_ws;
  float* ctx    = ws;                  // [8][16][768] = 98304
  float* denom  = ctx + 98304;         // [8][16]      = 128
  float* qv     = denom + 128;         // [8][768]     = 6144
  float* oat    = qv + 6144;           // [8][768]     = 6144
  float* lastb  = oat + 6144;          // [8][768]     = 6144
  float* hid    = lastb + 6144;        // [8][3072]    = 24576
  u16*   qWb    = (u16*)(hid + 24576); // [8][16][768] bf16

  hipMemsetAsync(ctx, 0, (size_t)(98304+128)*sizeof(float), stream);
  hipLaunchKernelGGL(k_q,    dim3(24,B_), dim3(256), 0, stream, x, Wq, bq, qv);
  hipLaunchKernelGGL(k_qw,   dim3(48,B_), dim3(256), 0, stream, qv, Wkv, qWb);
  hipLaunchKernelGGL(k_attn, dim3(64,B_), dim3(256), 0, stream, x, qWb, outp, ctx, denom);
  hipLaunchKernelGGL(k_v,    dim3(24,B_), dim3(256), 0, stream, ctx, denom, Wkv, bkv, oat);
  hipLaunchKernelGGL(k_o,    dim3(24,B_), dim3(256), 0, stream, x, oat, Wo, bo, lastb);
  hipLaunchKernelGGL(k_mlp1, dim3(192), dim3(256), 0, stream, lastb, W1, b1, hid);
  hipLaunchKernelGGL(k_mlp2, dim3(96), dim3(256), 0, stream, hid, W2, b2, lastb, outp);
}

// Round 9
// 109.972 us; speedup vs baseline: 1.1920x; 1.1920x over previous
//
#include <hip/hip_runtime.h>

#define B_ 8
#define N_ 4096
#define C_ 768
#define NP_ 4095
#define H_ 16
#define D_ 48
#define HID_ 3072
#define SCALE 0.14433756729740643f  // 1/sqrt(48)

typedef unsigned short u16;
typedef unsigned int u32;
typedef __attribute__((ext_vector_type(4))) float f32x4;
typedef __attribute__((ext_vector_type(8))) short short8;

__device__ __forceinline__ u32 f2bf_bits(float f){
  union { float f; u32 i; } v; v.f = f;
  return (v.i + 0x7fffu + ((v.i >> 16) & 1u)) >> 16;
}
__device__ __forceinline__ u16 f2bf(float f){ return (u16)f2bf_bits(f); }
__device__ __forceinline__ u32 pack2(float a, float b){
  return f2bf_bits(a) | (f2bf_bits(b) << 16);
}

// ---------------- k_q: qv[b,j] = LN(x[b,4095]) @ Wq[:,j] + bq[j] -------------
__global__ __launch_bounds__(256) void k_q(const float* __restrict__ x,
    const float* __restrict__ Wq, const float* __restrict__ bq,
    float* __restrict__ qv)
{
  int b = blockIdx.y, t = threadIdx.x;
  int j0 = blockIdx.x*32;
  __shared__ float xs[C_];
  __shared__ float red[32][9];
  __shared__ float redA[4], redB[4];
  const float* xr = x + ((size_t)b*N_ + NP_)*C_;
  float v0 = xr[t], v1 = xr[t+256], v2 = xr[t+512];
  float s = v0+v1+v2, q = v0*v0+v1*v1+v2*v2;
  #pragma unroll
  for (int off=32; off; off>>=1){ s += __shfl_xor(s,off); q += __shfl_xor(q,off); }
  int w = t>>6, l = t&63;
  if (l==0){ redA[w]=s; redB[w]=q; }
  __syncthreads();
  s = redA[0]+redA[1]+redA[2]+redA[3];
  q = redB[0]+redB[1]+redB[2]+redB[3];
  float mean = s*(1.f/C_), var = q*(1.f/C_) - mean*mean;
  float rstd = rsqrtf(var + 1e-6f);
  xs[t] = (v0-mean)*rstd; xs[t+256] = (v1-mean)*rstd; xs[t+512] = (v2-mean)*rstd;
  __syncthreads();
  int jl = t&31, part = t>>5;
  const float* wp = Wq + (size_t)(part*96)*C_ + j0 + jl;
  const float* xp = xs + part*96;
  float acc = 0.f;
  #pragma unroll 8
  for (int c=0;c<96;c++) acc += xp[c]*wp[(size_t)c*C_];
  red[jl][part] = acc;
  __syncthreads();
  if (part==0){
    float a = bq[j0+jl];
    #pragma unroll
    for (int p=0;p<8;p++) a += red[jl][p];
    qv[(size_t)b*C_ + j0 + jl] = a;
  }
}

// --- k_qw: qWb[b,h,c] = bf16( sum_d qv[b,h*48+d]*Wkv[c, h*48+d] ) ------------
__global__ __launch_bounds__(256) void k_qw(const float* __restrict__ qv,
    const float* __restrict__ Wkv, u16* __restrict__ qWb)
{
  int b = blockIdx.y, t = threadIdx.x;
  int c0 = blockIdx.x*16;
  __shared__ float qs[C_];
  for (int u=t; u<C_; u+=256) qs[u] = qv[(size_t)b*C_+u];
  __syncthreads();
  int h = t&15, cl = t>>4;
  int c = c0 + cl;
  const float* wp = Wkv + (size_t)c*(2*C_) + h*D_;
  const float* qh = qs + h*D_;
  float acc = 0.f;
  #pragma unroll
  for (int d=0; d<D_; d++) acc += qh[d]*wp[d];
  qWb[((size_t)b*H_ + h)*C_ + c] = f2bf(acc);
}

// ---- k_pre: 16-row tiles. copy + stats + K-split MFMA sim + exp.         ----
// ---- writes wrsT[b][h][k] (bf16), atomic denom[b][h], corr[b][h]         ----
__global__ __launch_bounds__(256) void k_pre(const float* __restrict__ x,
    const u16* __restrict__ qWb, float* __restrict__ outp,
    u16* __restrict__ wrsT, float* __restrict__ denom, float* __restrict__ corr)
{
  int b = blockIdx.y;
  int tid = threadIdx.x;
  int w = tid>>6, l = tid&63;
  int kblk = blockIdx.x*16;
  __shared__ u16 xn[16][776];        // normalized bf16 tile (pad: 388 dwords/row)
  __shared__ float2 stl[16];
  __shared__ float part[4][16][17];  // per-wave sim partials
  const size_t xb = (size_t)b*N_*C_;

  // ---- phase A: wave w -> rows w*4..w*4+3: copy, stats, pack->LDS ----
  #pragma unroll
  for (int i=0;i<4;i++){
    int r = w*4 + i;
    int kt = kblk + r;
    const float4* rp = (const float4*)(x + xb + (size_t)kt*C_);
    float4* op = (float4*)(outp + xb + (size_t)kt*C_);
    float4 v0 = rp[l], v1 = rp[l+64], v2 = rp[l+128];
    op[l] = v0; op[l+64] = v1; op[l+128] = v2;
    float s = v0.x+v0.y+v0.z+v0.w + v1.x+v1.y+v1.z+v1.w + v2.x+v2.y+v2.z+v2.w;
    float q = v0.x*v0.x+v0.y*v0.y+v0.z*v0.z+v0.w*v0.w
            + v1.x*v1.x+v1.y*v1.y+v1.z*v1.z+v1.w*v1.w
            + v2.x*v2.x+v2.y*v2.y+v2.z*v2.z+v2.w*v2.w;
    #pragma unroll
    for (int off=32; off; off>>=1){ s += __shfl_xor(s,off); q += __shfl_xor(q,off); }
    float mean = s*(1.f/C_), var = q*(1.f/C_) - mean*mean;
    float rstd = rsqrtf(var + 1e-6f);
    if (l==0) stl[r] = make_float2(mean, rstd);
    u32* xrow = (u32*)&xn[r][0];
    xrow[2*l]       = pack2((v0.x-mean)*rstd, (v0.y-mean)*rstd);
    xrow[2*l+1]     = pack2((v0.z-mean)*rstd, (v0.w-mean)*rstd);
    xrow[128+2*l]   = pack2((v1.x-mean)*rstd, (v1.y-mean)*rstd);
    xrow[128+2*l+1] = pack2((v1.z-mean)*rstd, (v1.w-mean)*rstd);
    xrow[256+2*l]   = pack2((v2.x-mean)*rstd, (v2.y-mean)*rstd);
    xrow[256+2*l+1] = pack2((v2.z-mean)*rstd, (v2.w-mean)*rstd);
  }
  __syncthreads();

  // ---- phase B: wave w -> K-chunk [w*192, w*192+192), 16 rows x 16 heads ----
  {
    int arow = l&15;
    int ko = w*192 + (l>>4)*8;
    const u16* brb = qWb + ((size_t)b*H_ + (l&15))*C_ + ko;
    f32x4 acc = {0.f,0.f,0.f,0.f};
    #pragma unroll
    for (int s2=0;s2<6;s2++){
      union{uint4 u; short8 v;} A, Bf;
      A.u  = *(const uint4*)&xn[arow][ko + s2*32];
      Bf.u = *(const uint4*)(brb + s2*32);
      acc = __builtin_amdgcn_mfma_f32_16x16x32_bf16(A.v, Bf.v, acc, 0,0,0);
    }
    int mb = (l>>4)*4, n = l&15;
    #pragma unroll
    for (int r=0;r<4;r++) part[w][mb+r][n] = acc[r];
  }
  __syncthreads();

  // ---- phase C: thread t = (m,n): total sim, exp, wrsT, reductions ----
  {
    int m = tid>>4, n = tid&15;
    float sim = part[0][m][n] + part[1][m][n] + part[2][m][n] + part[3][m][n];
    int kt = kblk + m;
    float2 ms = stl[m];
    float wv = (kt < NP_) ? __expf(sim*SCALE) : 0.f;
    float wrs = wv * ms.y;
    wrsT[((size_t)b*H_ + n)*N_ + kt] = f2bf(wrs);
    part[0][m][n] = wv;
    part[1][m][n] = wrs * ms.x;
  }
  __syncthreads();
  if (tid < 16){
    float ds = 0.f, cs = 0.f;
    #pragma unroll
    for (int m=0;m<16;m++){ ds += part[0][m][tid]; cs += part[1][m][tid]; }
    atomicAdd(denom + (size_t)b*H_ + tid, ds);
    atomicAdd(corr  + (size_t)b*H_ + tid, cs);
  }
}

// ---- k_ctx2: ctx[b,h,c] = sum_k wrsT[b][h][k]*x[b][k][c] via MFMA GEMM   ----
// ---- grid: (12 colgroups x 8 ksplits, 8 batches); corr applied in k_v    ----
__global__ __launch_bounds__(256) void k_ctx2(const float* __restrict__ x,
    const u16* __restrict__ wrsT, float* __restrict__ ctx)
{
  int b = blockIdx.y;
  int cg = blockIdx.x % 12;
  int ks = blockIdx.x / 12;
  int tid = threadIdx.x;
  int w = tid>>6, l = tid&63;
  int ctile = cg*64 + w*16;
  int k0 = ks*512;
  const size_t xb = (size_t)b*N_*C_;
  const u16* ap = wrsT + ((size_t)b*H_ + (l&15))*N_ + k0 + (l>>4)*8;
  const float* bp = x + xb + (size_t)(k0 + (l>>4)*8)*C_ + ctile + (l&15);
  f32x4 acc = {0.f,0.f,0.f,0.f};
  for (int s=0;s<16;s++){
    union{uint4 u; short8 v;} A, Bf;
    A.u = *(const uint4*)(ap + s*32);
    const float* bq2 = bp + (size_t)s*32*C_;
    float x0 = bq2[0];
    float x1 = bq2[(size_t)1*C_];
    float x2 = bq2[(size_t)2*C_];
    float x3 = bq2[(size_t)3*C_];
    float x4 = bq2[(size_t)4*C_];
    float x5 = bq2[(size_t)5*C_];
    float x6 = bq2[(size_t)6*C_];
    float x7 = bq2[(size_t)7*C_];
    uint4 nb;
    nb.x = pack2(x0,x1); nb.y = pack2(x2,x3);
    nb.z = pack2(x4,x5); nb.w = pack2(x6,x7);
    Bf.u = nb;
    acc = __builtin_amdgcn_mfma_f32_16x16x32_bf16(A.v, Bf.v, acc, 0,0,0);
  }
  // D[m=h][n=c]: h=(l>>4)*4+r, c=ctile+(l&15)
  int cc = ctile + (l&15);
  float* cb = ctx + (size_t)b*H_*C_;
  #pragma unroll
  for (int r=0;r<4;r++){
    int h = (l>>4)*4 + r;
    atomicAdd(cb + h*C_ + cc, acc[r]);
  }
}

// ------ k_v: oat[b,t] = ((ctx-corr)/denom)[b,h(t),:] @ Wv[:,t] + bv[t] -------
__global__ __launch_bounds__(256) void k_v(const float* __restrict__ ctx,
    const float* __restrict__ denom, const float* __restrict__ corr,
    const float* __restrict__ Wkv, const float* __restrict__ bkv,
    float* __restrict__ oat)
{
  int b = blockIdx.y, t = threadIdx.x;
  int t0 = blockIdx.x*32;
  int h0 = t0/D_;
  int h1 = (t0+31)/D_; if (h1 > H_-1) h1 = H_-1;
  __shared__ float cn[2][C_];
  __shared__ float red[32][9];
  float inv0 = 1.f/denom[(size_t)b*H_+h0];
  float inv1 = 1.f/denom[(size_t)b*H_+h1];
  float cr0 = corr[(size_t)b*H_+h0];
  float cr1 = corr[(size_t)b*H_+h1];
  for (int u=t; u<C_; u+=256){
    cn[0][u] = (ctx[((size_t)b*H_+h0)*C_+u] - cr0)*inv0;
    cn[1][u] = (ctx[((size_t)b*H_+h1)*C_+u] - cr1)*inv1;
  }
  __syncthreads();
  int jl = t&31, part = t>>5;
  int tt = t0 + jl;
  int hi = (tt/D_) - h0;   // 0 or 1
  const float* wp = Wkv + (size_t)(part*96)*(2*C_) + C_ + tt;
  const float* cp = cn[hi] + part*96;
  float acc = 0.f;
  #pragma unroll 8
  for (int c=0;c<96;c++) acc += cp[c]*wp[(size_t)c*(2*C_)];
  red[jl][part] = acc;
  __syncthreads();
  if (part==0){
    float a = bkv[C_ + tt];
    #pragma unroll
    for (int p=0;p<8;p++) a += red[jl][p];
    oat[(size_t)b*C_ + tt] = a;
  }
}

// ------- k_o: lastb[b,t] = x[b,4095,t] + oat[b] @ Wo[:,t] + bo[t] ------------
__global__ __launch_bounds__(256) void k_o(const float* __restrict__ x,
    const float* __restrict__ oat, const float* __restrict__ Wo,
    const float* __restrict__ bo, float* __restrict__ lastb)
{
  int b = blockIdx.y, t = threadIdx.x;
  int t0 = blockIdx.x*32;
  __shared__ float xs[C_];
  __shared__ float red[32][9];
  for (int u=t; u<C_; u+=256) xs[u] = oat[(size_t)b*C_+u];
  __syncthreads();
  int jl = t&31, part = t>>5;
  int tt = t0 + jl;
  const float* wp = Wo + (size_t)(part*96)*C_ + tt;
  const float* xp = xs + part*96;
  float acc = 0.f;
  #pragma unroll 8
  for (int c=0;c<96;c++) acc += xp[c]*wp[(size_t)c*C_];
  red[jl][part] = acc;
  __syncthreads();
  if (part==0){
    float a = bo[tt];
    #pragma unroll
    for (int p=0;p<8;p++) a += red[jl][p];
    lastb[(size_t)b*C_ + tt] = x[((size_t)b*N_ + NP_)*C_ + tt] + a;
  }
}

// --- k_mlp1 (batched): hid[b] = gelu(LN(lastb[b]) @ W1 + b1), W1 read once ---
__global__ __launch_bounds__(256) void k_mlp1(const float* __restrict__ lastb,
    const float* __restrict__ W1, const float* __restrict__ b1,
    float* __restrict__ hid)
{
  int t = threadIdx.x;
  int j0 = blockIdx.x*16;
  __shared__ float xs[B_][C_];
  __shared__ float red[16][16][8];
  {
    int bb = t>>5, sub = t&31;
    const float* xr = lastb + (size_t)bb*C_;
    float s=0.f, q=0.f;
    #pragma unroll
    for (int j=0;j<24;j++){ float v = xr[sub+32*j]; s += v; q += v*v; }
    #pragma unroll
    for (int off=1; off<32; off<<=1){ s += __shfl_xor(s,off); q += __shfl_xor(q,off); }
    float mean = s*(1.f/C_), var = q*(1.f/C_) - mean*mean;
    float rstd = rsqrtf(var + 1e-6f);
    #pragma unroll
    for (int j=0;j<24;j++){ xs[bb][sub+32*j] = (xr[sub+32*j]-mean)*rstd; }
  }
  __syncthreads();
  int jl = t&15, part = t>>4;
  const float* wp = W1 + (size_t)(part*48)*HID_ + j0 + jl;
  float acc[B_];
  #pragma unroll
  for (int bb=0;bb<B_;bb++) acc[bb]=0.f;
  for (int c=0;c<48;c++){
    float wv = wp[(size_t)c*HID_];
    int cc = part*48 + c;
    #pragma unroll
    for (int bb=0;bb<B_;bb++) acc[bb] += xs[bb][cc]*wv;
  }
  #pragma unroll
  for (int bb=0;bb<B_;bb++) red[jl][part][bb] = acc[bb];
  __syncthreads();
  if (t < 128){
    int jl2 = t&15, bb = t>>4;
    float a = b1[j0+jl2];
    #pragma unroll
    for (int p=0;p<16;p++) a += red[jl2][p][bb];
    float t3 = a + 0.044715f*a*a*a;
    float g = 0.5f*a*(1.f + tanhf(0.7978845608f*t3));
    hid[(size_t)bb*HID_ + j0 + jl2] = g;
  }
}

// --- k_mlp2 (batched): out[b,4095,:] = lastb[b] + hid[b] @ W2 + b2 -----------
__global__ __launch_bounds__(256) void k_mlp2(const float* __restrict__ hid,
    const float* __restrict__ W2, const float* __restrict__ b2,
    const float* __restrict__ lastb, float* __restrict__ outp)
{
  int t = threadIdx.x;
  int c0 = blockIdx.x*8;
  __shared__ float red[8][32][8];
  int ccl = t&7, part = t>>3;
  const float* wp = W2 + (size_t)(part*96)*C_ + c0 + ccl;
  float acc[B_];
  #pragma unroll
  for (int bb=0;bb<B_;bb++) acc[bb]=0.f;
  for (int j=0;j<96;j++){
    float wv = wp[(size_t)j*C_];
    int jj = part*96 + j;
    #pragma unroll
    for (int bb=0;bb<B_;bb++) acc[bb] += hid[(size_t)bb*HID_ + jj]*wv;
  }
  #pragma unroll
  for (int bb=0;bb<B_;bb++) red[ccl][part][bb] = acc[bb];
  __syncthreads();
  if (t < 64){
    int cc2 = t&7, bb = t>>3;
    float a = 0.f;
    #pragma unroll
    for (int p=0;p<32;p++) a += red[cc2][p][bb];
    int cc = c0 + cc2;
    a += b2[cc] + lastb[(size_t)bb*C_ + cc];
    outp[((size_t)bb*N_ + NP_)*C_ + cc] = a;
  }
}

extern "C" void kernel_launch(void* const* d_in, const int* in_sizes, int n_in,
                              void* d_out, int out_size, void* d_ws, size_t ws_size,
                              hipStream_t stream)
{
  (void)in_sizes; (void)n_in; (void)out_size; (void)ws_size;
  const float* x   = (const float*)d_in[0];
  const float* Wq  = (const float*)d_in[1];
  const float* bq  = (const float*)d_in[2];
  const float* Wkv = (const float*)d_in[3];
  const float* bkv = (const float*)d_in[4];
  const float* Wo  = (const float*)d_in[5];
  const float* bo  = (const float*)d_in[6];
  const float* W1  = (const float*)d_in[7];
  const float* b1  = (const float*)d_in[8];
  const float* W2  = (const float*)d_in[9];
  const float* b2  = (const float*)d_in[10];
  float* outp = (float*)d_out;
  float* ws = (float*)d_ws;
  float* ctx    = ws;                    // [8][16][768] = 98304
  float* denom  = ctx + 98304;           // [8][16]      = 128
  float* corr   = denom + 128;           // [8][16]      = 128
  float* qv     = corr + 128;            // [8][768]     = 6144
  float* oat    = qv + 6144;             // [8][768]     = 6144
  float* lastb  = oat + 6144;            // [8][768]     = 6144
  float* hid    = lastb + 6144;          // [8][3072]    = 24576
  u16*   qWb    = (u16*)(hid + 24576);   // [8][16][768] bf16 = 49152 f32-slots
  u16*   wrsT   = (u16*)(hid + 24576 + 49152); // [8][16][4096] bf16 = 262144 f32-slots

  hipMemsetAsync(ctx, 0, (size_t)(98304+256)*sizeof(float), stream);
  hipLaunchKernelGGL(k_q,    dim3(24,B_), dim3(256), 0, stream, x, Wq, bq, qv);
  hipLaunchKernelGGL(k_qw,   dim3(48,B_), dim3(256), 0, stream, qv, Wkv, qWb);
  hipLaunchKernelGGL(k_pre,  dim3(256,B_), dim3(256), 0, stream, x, qWb, outp, wrsT, denom, corr);
  hipLaunchKernelGGL(k_ctx2, dim3(96,B_), dim3(256), 0, stream, x, wrsT, ctx);
  hipLaunchKernelGGL(k_v,    dim3(24,B_), dim3(256), 0, stream, ctx, denom, corr, Wkv, bkv, oat);
  hipLaunchKernelGGL(k_o,    dim3(24,B_), dim3(256), 0, stream, x, oat, Wo, bo, lastb);
  hipLaunchKernelGGL(k_mlp1, dim3(192), dim3(256), 0, stream, lastb, W1, b1, hid);
  hipLaunchKernelGGL(k_mlp2, dim3(96), dim3(256), 0, stream, hid, W2, b2, lastb, outp);
}

// Round 10
// 109.659 us; speedup vs baseline: 1.1954x; 1.0029x over previous
//
#include <hip/hip_runtime.h>

#define B_ 8
#define N_ 4096
#define C_ 768
#define NP_ 4095
#define H_ 16
#define D_ 48
#define HID_ 3072
#define SCALE 0.14433756729740643f  // 1/sqrt(48)

typedef unsigned short u16;
typedef unsigned int u32;
typedef __attribute__((ext_vector_type(4))) float f32x4;
typedef __attribute__((ext_vector_type(8))) short short8;

__device__ __forceinline__ u32 f2bf_bits(float f){
  union { float f; u32 i; } v; v.f = f;
  return (v.i + 0x7fffu + ((v.i >> 16) & 1u)) >> 16;
}
__device__ __forceinline__ u16 f2bf(float f){ return (u16)f2bf_bits(f); }
__device__ __forceinline__ float bf2f(u16 u){
  union { u32 i; float f; } v; v.i = ((u32)u) << 16; return v.f;
}
__device__ __forceinline__ u32 pack2(float a, float b){
  return f2bf_bits(a) | (f2bf_bits(b) << 16);
}

// -------- k_q: zero ctx/denom/corr + qv[b,j] = LN(x[b,4095]) @ Wq + bq -------
__global__ __launch_bounds__(256) void k_q(const float* __restrict__ x,
    const float* __restrict__ Wq, const float* __restrict__ bq,
    float* __restrict__ qv, float* __restrict__ zbase)
{
  int b = blockIdx.y, t = threadIdx.x;
  int j0 = blockIdx.x*32;
  // zero ctx(98304) + denom(128) + corr(128) = 98560 floats
  {
    int gid = (b*24 + blockIdx.x)*256 + t;
    for (int u = gid; u < 98560; u += 49152) zbase[u] = 0.f;
  }
  __shared__ float xs[C_];
  __shared__ float red[32][9];
  __shared__ float redA[4], redB[4];
  const float* xr = x + ((size_t)b*N_ + NP_)*C_;
  float v0 = xr[t], v1 = xr[t+256], v2 = xr[t+512];
  float s = v0+v1+v2, q = v0*v0+v1*v1+v2*v2;
  #pragma unroll
  for (int off=32; off; off>>=1){ s += __shfl_xor(s,off); q += __shfl_xor(q,off); }
  int w = t>>6, l = t&63;
  if (l==0){ redA[w]=s; redB[w]=q; }
  __syncthreads();
  s = redA[0]+redA[1]+redA[2]+redA[3];
  q = redB[0]+redB[1]+redB[2]+redB[3];
  float mean = s*(1.f/C_), var = q*(1.f/C_) - mean*mean;
  float rstd = rsqrtf(var + 1e-6f);
  xs[t] = (v0-mean)*rstd; xs[t+256] = (v1-mean)*rstd; xs[t+512] = (v2-mean)*rstd;
  __syncthreads();
  int jl = t&31, part = t>>5;
  const float* wp = Wq + (size_t)(part*96)*C_ + j0 + jl;
  const float* xp = xs + part*96;
  float acc = 0.f;
  #pragma unroll 8
  for (int c=0;c<96;c++) acc += xp[c]*wp[(size_t)c*C_];
  red[jl][part] = acc;
  __syncthreads();
  if (part==0){
    float a = bq[j0+jl];
    #pragma unroll
    for (int p=0;p<8;p++) a += red[jl][p];
    qv[(size_t)b*C_ + j0 + jl] = a;
  }
}

// --- k_qw: qWb[b,h,c] = bf16( sum_d qv[b,h*48+d]*Wkv[c, h*48+d] ) ------------
__global__ __launch_bounds__(256) void k_qw(const float* __restrict__ qv,
    const float* __restrict__ Wkv, u16* __restrict__ qWb)
{
  int b = blockIdx.y, t = threadIdx.x;
  int c0 = blockIdx.x*16;
  __shared__ float qs[C_];
  for (int u=t; u<C_; u+=256) qs[u] = qv[(size_t)b*C_+u];
  __syncthreads();
  int h = t&15, cl = t>>4;
  int c = c0 + cl;
  const float* wp = Wkv + (size_t)c*(2*C_) + h*D_;
  const float* qh = qs + h*D_;
  float acc = 0.f;
  #pragma unroll
  for (int d=0; d<D_; d++) acc += qh[d]*wp[d];
  qWb[((size_t)b*H_ + h)*C_ + c] = f2bf(acc);
}

// ---- k_pre v2: 16-row tiles, NO xn LDS. Fragment-order x read:           ----
// ---- copy->out + stats(shfl+tiny LDS) + in-reg normalize/pack + MFMA.    ----
// ---- Writes wrsT (bf16), atomic denom/corr.                              ----
__global__ __launch_bounds__(256) void k_pre(const float* __restrict__ x,
    const u16* __restrict__ qWb, float* __restrict__ outp,
    u16* __restrict__ wrsT, float* __restrict__ denom, float* __restrict__ corr)
{
  int b = blockIdx.y;
  int tid = threadIdx.x;
  int w = tid>>6, l = tid&63;
  int kblk = blockIdx.x*16;
  __shared__ float smean[4][16], ssq[4][16];
  __shared__ float2 stl[16];
  __shared__ float part[4][16][17];
  const size_t xb = (size_t)b*N_*C_;

  int r = l & 15;                    // A-fragment row (and B head index)
  int row = kblk + r;
  int cb = w*192 + ((l>>4)<<3);      // lane's k-slice base within K
  const float* xp = x + xb + (size_t)row*C_ + cb;
  float* op = outp + xb + (size_t)row*C_ + cb;

  // load 48 floats in fragment order; copy to out; partial stats
  float4 g[12];
  float s = 0.f, q = 0.f;
  #pragma unroll
  for (int s2=0; s2<6; ++s2){
    float4 a0 = *(const float4*)(xp + s2*32);
    float4 a1 = *(const float4*)(xp + s2*32 + 4);
    g[2*s2] = a0; g[2*s2+1] = a1;
    *(float4*)(op + s2*32)     = a0;
    *(float4*)(op + s2*32 + 4) = a1;
    s += a0.x+a0.y+a0.z+a0.w + a1.x+a1.y+a1.z+a1.w;
    q += a0.x*a0.x+a0.y*a0.y+a0.z*a0.z+a0.w*a0.w
       + a1.x*a1.x+a1.y*a1.y+a1.z*a1.z+a1.w*a1.w;
  }
  // reduce over the 4 lanes sharing this row within the wave
  s += __shfl_xor(s,16); q += __shfl_xor(q,16);
  s += __shfl_xor(s,32); q += __shfl_xor(q,32);
  if (l < 16){ smean[w][l] = s; ssq[w][l] = q; }
  __syncthreads();
  float fs = smean[0][r]+smean[1][r]+smean[2][r]+smean[3][r];
  float fq = ssq[0][r]+ssq[1][r]+ssq[2][r]+ssq[3][r];
  float mean = fs*(1.f/C_), var = fq*(1.f/C_) - mean*mean;
  float rstd = rsqrtf(var + 1e-6f);
  if (tid < 16) stl[tid] = make_float2(mean, rstd);

  // normalize + pack to bf16 A-fragments, K-split MFMA (chunk w)
  const u16* brb = qWb + ((size_t)b*H_ + r)*C_ + cb;
  f32x4 acc = {0.f,0.f,0.f,0.f};
  #pragma unroll
  for (int s2=0;s2<6;s2++){
    float4 a0 = g[2*s2], a1 = g[2*s2+1];
    union{uint4 u; short8 v;} A, Bf;
    A.u.x = pack2((a0.x-mean)*rstd, (a0.y-mean)*rstd);
    A.u.y = pack2((a0.z-mean)*rstd, (a0.w-mean)*rstd);
    A.u.z = pack2((a1.x-mean)*rstd, (a1.y-mean)*rstd);
    A.u.w = pack2((a1.z-mean)*rstd, (a1.w-mean)*rstd);
    Bf.u = *(const uint4*)(brb + s2*32);
    acc = __builtin_amdgcn_mfma_f32_16x16x32_bf16(A.v, Bf.v, acc, 0,0,0);
  }
  {
    int mb = (l>>4)*4, n = l&15;
    #pragma unroll
    for (int r4=0;r4<4;r4++) part[w][mb+r4][n] = acc[r4];
  }
  __syncthreads();

  // phase C: thread (m,n) -> sim total, exp, wrsT write
  {
    int m = tid>>4, n = tid&15;
    float sim = part[0][m][n] + part[1][m][n] + part[2][m][n] + part[3][m][n];
    int kt = kblk + m;
    float2 ms = stl[m];
    float wv = (kt < NP_) ? __expf(sim*SCALE) : 0.f;
    u16 wb = f2bf(wv * ms.y);
    wrsT[((size_t)b*H_ + n)*N_ + kt] = wb;
    part[0][m][n] = wv;
    part[1][m][n] = bf2f(wb) * ms.x;
  }
  __syncthreads();
  if (tid < 16){
    float ds = 0.f, cs = 0.f;
    #pragma unroll
    for (int m=0;m<16;m++){ ds += part[0][m][tid]; cs += part[1][m][tid]; }
    atomicAdd(denom + (size_t)b*H_ + tid, ds);
    atomicAdd(corr  + (size_t)b*H_ + tid, cs);
  }
}

// ---- k_ctx2: ctx[b,h,c] = sum_k wrsT[b][h][k]*x[b][k][c] via MFMA GEMM   ----
__global__ __launch_bounds__(256) void k_ctx2(const float* __restrict__ x,
    const u16* __restrict__ wrsT, float* __restrict__ ctx)
{
  int b = blockIdx.y;
  int cg = blockIdx.x % 12;
  int ks = blockIdx.x / 12;
  int tid = threadIdx.x;
  int w = tid>>6, l = tid&63;
  int ctile = cg*64 + w*16;
  int k0 = ks*512;
  const size_t xb = (size_t)b*N_*C_;
  const u16* ap = wrsT + ((size_t)b*H_ + (l&15))*N_ + k0 + (l>>4)*8;
  const float* bp = x + xb + (size_t)(k0 + (l>>4)*8)*C_ + ctile + (l&15);
  f32x4 acc = {0.f,0.f,0.f,0.f};
  for (int s=0;s<16;s++){
    union{uint4 u; short8 v;} A, Bf;
    A.u = *(const uint4*)(ap + s*32);
    const float* bq2 = bp + (size_t)s*32*C_;
    float x0 = bq2[0];
    float x1 = bq2[(size_t)1*C_];
    float x2 = bq2[(size_t)2*C_];
    float x3 = bq2[(size_t)3*C_];
    float x4 = bq2[(size_t)4*C_];
    float x5 = bq2[(size_t)5*C_];
    float x6 = bq2[(size_t)6*C_];
    float x7 = bq2[(size_t)7*C_];
    uint4 nb;
    nb.x = pack2(x0,x1); nb.y = pack2(x2,x3);
    nb.z = pack2(x4,x5); nb.w = pack2(x6,x7);
    Bf.u = nb;
    acc = __builtin_amdgcn_mfma_f32_16x16x32_bf16(A.v, Bf.v, acc, 0,0,0);
  }
  int cc = ctile + (l&15);
  float* cb = ctx + (size_t)b*H_*C_;
  #pragma unroll
  for (int r=0;r<4;r++){
    int h = (l>>4)*4 + r;
    atomicAdd(cb + h*C_ + cc, acc[r]);
  }
}

// ------ k_v: oat[b,t] = ((ctx-corr)/denom)[b,h(t),:] @ Wv[:,t] + bv[t] -------
__global__ __launch_bounds__(256) void k_v(const float* __restrict__ ctx,
    const float* __restrict__ denom, const float* __restrict__ corr,
    const float* __restrict__ Wkv, const float* __restrict__ bkv,
    float* __restrict__ oat)
{
  int b = blockIdx.y, t = threadIdx.x;
  int t0 = blockIdx.x*32;
  int h0 = t0/D_;
  int h1 = (t0+31)/D_; if (h1 > H_-1) h1 = H_-1;
  __shared__ float cn[2][C_];
  __shared__ float red[32][9];
  float inv0 = 1.f/denom[(size_t)b*H_+h0];
  float inv1 = 1.f/denom[(size_t)b*H_+h1];
  float cr0 = corr[(size_t)b*H_+h0];
  float cr1 = corr[(size_t)b*H_+h1];
  for (int u=t; u<C_; u+=256){
    cn[0][u] = (ctx[((size_t)b*H_+h0)*C_+u] - cr0)*inv0;
    cn[1][u] = (ctx[((size_t)b*H_+h1)*C_+u] - cr1)*inv1;
  }
  __syncthreads();
  int jl = t&31, part = t>>5;
  int tt = t0 + jl;
  int hi = (tt/D_) - h0;   // 0 or 1
  const float* wp = Wkv + (size_t)(part*96)*(2*C_) + C_ + tt;
  const float* cp = cn[hi] + part*96;
  float acc = 0.f;
  #pragma unroll 8
  for (int c=0;c<96;c++) acc += cp[c]*wp[(size_t)c*(2*C_)];
  red[jl][part] = acc;
  __syncthreads();
  if (part==0){
    float a = bkv[C_ + tt];
    #pragma unroll
    for (int p=0;p<8;p++) a += red[jl][p];
    oat[(size_t)b*C_ + tt] = a;
  }
}

// ------- k_o: lastb[b,t] = x[b,4095,t] + oat[b] @ Wo[:,t] + bo[t] ------------
__global__ __launch_bounds__(256) void k_o(const float* __restrict__ x,
    const float* __restrict__ oat, const float* __restrict__ Wo,
    const float* __restrict__ bo, float* __restrict__ lastb)
{
  int b = blockIdx.y, t = threadIdx.x;
  int t0 = blockIdx.x*32;
  __shared__ float xs[C_];
  __shared__ float red[32][9];
  for (int u=t; u<C_; u+=256) xs[u] = oat[(size_t)b*C_+u];
  __syncthreads();
  int jl = t&31, part = t>>5;
  int tt = t0 + jl;
  const float* wp = Wo + (size_t)(part*96)*C_ + tt;
  const float* xp = xs + part*96;
  float acc = 0.f;
  #pragma unroll 8
  for (int c=0;c<96;c++) acc += xp[c]*wp[(size_t)c*C_];
  red[jl][part] = acc;
  __syncthreads();
  if (part==0){
    float a = bo[tt];
    #pragma unroll
    for (int p=0;p<8;p++) a += red[jl][p];
    lastb[(size_t)b*C_ + tt] = x[((size_t)b*N_ + NP_)*C_ + tt] + a;
  }
}

// --- k_mlp1 (batched): hid[b] = gelu(LN(lastb[b]) @ W1 + b1), W1 read once ---
__global__ __launch_bounds__(256) void k_mlp1(const float* __restrict__ lastb,
    const float* __restrict__ W1, const float* __restrict__ b1,
    float* __restrict__ hid)
{
  int t = threadIdx.x;
  int j0 = blockIdx.x*16;
  __shared__ float xs[B_][C_];
  __shared__ float red[16][16][8];
  {
    int bb = t>>5, sub = t&31;
    const float* xr = lastb + (size_t)bb*C_;
    float s=0.f, q=0.f;
    #pragma unroll
    for (int j=0;j<24;j++){ float v = xr[sub+32*j]; s += v; q += v*v; }
    #pragma unroll
    for (int off=1; off<32; off<<=1){ s += __shfl_xor(s,off); q += __shfl_xor(q,off); }
    float mean = s*(1.f/C_), var = q*(1.f/C_) - mean*mean;
    float rstd = rsqrtf(var + 1e-6f);
    #pragma unroll
    for (int j=0;j<24;j++){ xs[bb][sub+32*j] = (xr[sub+32*j]-mean)*rstd; }
  }
  __syncthreads();
  int jl = t&15, part = t>>4;
  const float* wp = W1 + (size_t)(part*48)*HID_ + j0 + jl;
  float acc[B_];
  #pragma unroll
  for (int bb=0;bb<B_;bb++) acc[bb]=0.f;
  for (int c=0;c<48;c++){
    float wv = wp[(size_t)c*HID_];
    int cc = part*48 + c;
    #pragma unroll
    for (int bb=0;bb<B_;bb++) acc[bb] += xs[bb][cc]*wv;
  }
  #pragma unroll
  for (int bb=0;bb<B_;bb++) red[jl][part][bb] = acc[bb];
  __syncthreads();
  if (t < 128){
    int jl2 = t&15, bb = t>>4;
    float a = b1[j0+jl2];
    #pragma unroll
    for (int p=0;p<16;p++) a += red[jl2][p][bb];
    float t3 = a + 0.044715f*a*a*a;
    float g = 0.5f*a*(1.f + tanhf(0.7978845608f*t3));
    hid[(size_t)bb*HID_ + j0 + jl2] = g;
  }
}

// --- k_mlp2 (batched): out[b,4095,:] = lastb[b] + hid[b] @ W2 + b2 -----------
__global__ __launch_bounds__(256) void k_mlp2(const float* __restrict__ hid,
    const float* __restrict__ W2, const float* __restrict__ b2,
    const float* __restrict__ lastb, float* __restrict__ outp)
{
  int t = threadIdx.x;
  int c0 = blockIdx.x*8;
  __shared__ float red[8][32][8];
  int ccl = t&7, part = t>>3;
  const float* wp = W2 + (size_t)(part*96)*C_ + c0 + ccl;
  float acc[B_];
  #pragma unroll
  for (int bb=0;bb<B_;bb++) acc[bb]=0.f;
  for (int j=0;j<96;j++){
    float wv = wp[(size_t)j*C_];
    int jj = part*96 + j;
    #pragma unroll
    for (int bb=0;bb<B_;bb++) acc[bb] += hid[(size_t)bb*HID_ + jj]*wv;
  }
  #pragma unroll
  for (int bb=0;bb<B_;bb++) red[ccl][part][bb] = acc[bb];
  __syncthreads();
  if (t < 64){
    int cc2 = t&7, bb = t>>3;
    float a = 0.f;
    #pragma unroll
    for (int p=0;p<32;p++) a += red[cc2][p][bb];
    int cc = c0 + cc2;
    a += b2[cc] + lastb[(size_t)bb*C_ + cc];
    outp[((size_t)bb*N_ + NP_)*C_ + cc] = a;
  }
}

extern "C" void kernel_launch(void* const* d_in, const int* in_sizes, int n_in,
                              void* d_out, int out_size, void* d_ws, size_t ws_size,
                              hipStream_t stream)
{
  (void)in_sizes; (void)n_in; (void)out_size; (void)ws_size;
  const float* x   = (const float*)d_in[0];
  const float* Wq  = (const float*)d_in[1];
  const float* bq  = (const float*)d_in[2];
  const float* Wkv = (const float*)d_in[3];
  const float* bkv = (const float*)d_in[4];
  const float* Wo  = (const float*)d_in[5];
  const float* bo  = (const float*)d_in[6];
  const float* W1  = (const float*)d_in[7];
  const float* b1  = (const float*)d_in[8];
  const float* W2  = (const float*)d_in[9];
  const float* b2  = (const float*)d_in[10];
  float* outp = (float*)d_out;
  float* ws = (float*)d_ws;
  float* ctx    = ws;                    // [8][16][768] = 98304
  float* denom  = ctx + 98304;           // [8][16]      = 128
  float* corr   = denom + 128;           // [8][16]      = 128
  float* qv     = corr + 128;            // [8][768]     = 6144
  float* oat    = qv + 6144;             // [8][768]     = 6144
  float* lastb  = oat + 6144;            // [8][768]     = 6144
  float* hid    = lastb + 6144;          // [8][3072]    = 24576
  u16*   qWb    = (u16*)(hid + 24576);   // [8][16][768] bf16
  u16*   wrsT   = (u16*)(hid + 24576 + 49152); // [8][16][4096] bf16

  hipLaunchKernelGGL(k_q,    dim3(24,B_), dim3(256), 0, stream, x, Wq, bq, qv, ctx);
  hipLaunchKernelGGL(k_qw,   dim3(48,B_), dim3(256), 0, stream, qv, Wkv, qWb);
  hipLaunchKernelGGL(k_pre,  dim3(256,B_), dim3(256), 0, stream, x, qWb, outp, wrsT, denom, corr);
  hipLaunchKernelGGL(k_ctx2, dim3(96,B_), dim3(256), 0, stream, x, wrsT, ctx);
  hipLaunchKernelGGL(k_v,    dim3(24,B_), dim3(256), 0, stream, ctx, denom, corr, Wkv, bkv, oat);
  hipLaunchKernelGGL(k_o,    dim3(24,B_), dim3(256), 0, stream, x, oat, Wo, bo, lastb);
  hipLaunchKernelGGL(k_mlp1, dim3(192), dim3(256), 0, stream, lastb, W1, b1, hid);
  hipLaunchKernelGGL(k_mlp2, dim3(96), dim3(256), 0, stream, hid, W2, b2, lastb, outp);
}